// Round 2
// baseline (2998.863 us; speedup 1.0000x reference)
//
#include <hip/hip_runtime.h>
#include <hip/hip_bf16.h>

// Problem constants (fixed by the reference): B=2, T=2048, C=1024, H=16, D=64
#define B_ 2
#define T_ 2048
#define C_ 1024
#define H_ 16
#define D_ 64
#define M_ (B_ * T_)   // 4096 rows of x
#define N3C (3 * C_)   // 3072

// ---------------- ternarization ----------------

__global__ void zero_sums(double* sums) {
  if (threadIdx.x < 2) sums[threadIdx.x] = 0.0;
}

__global__ void abs_sum_kernel(const float* __restrict__ w, int n4, double* out) {
  int stride = gridDim.x * blockDim.x;
  double s = 0.0;
  for (int i = blockIdx.x * blockDim.x + threadIdx.x; i < n4; i += stride) {
    float4 v = ((const float4*)w)[i];
    s += (double)fabsf(v.x) + (double)fabsf(v.y) + (double)fabsf(v.z) + (double)fabsf(v.w);
  }
  #pragma unroll
  for (int off = 32; off > 0; off >>= 1)
    s += __shfl_down(s, off, 64);
  if ((threadIdx.x & 63) == 0) atomicAdd(out, s);
}

// out gets exact {-1, 0, +1} in fp32; abs_mean scale applied in GEMM epilogue
__global__ void ternarize_kernel(const float* __restrict__ w, float* __restrict__ out, int n,
                                 const double* sum, float inv_n, float* am_out) {
  float am = fmaxf((float)(*sum) * inv_n, 1e-5f);
  int i = blockIdx.x * blockDim.x + threadIdx.x;
  if (i == 0) *am_out = am;
  if (i < n) {
    float thr = 0.7f * am;
    float x = w[i];
    out[i] = (x > thr) ? 1.0f : ((x < -thr) ? -1.0f : 0.0f);
  }
}

// ---------------- GEMM: C[M,N] = (A[M,K] @ W[N,K]^T) * scale ----------------
// 64x64 tile, BK=32, 256 threads, 4x4 micro-tile, fp32 accumulate.

__global__ __launch_bounds__(256) void gemm_bt(const float* __restrict__ A,
                                               const float* __restrict__ W,
                                               const float* __restrict__ scale_ptr,
                                               float* __restrict__ Co,
                                               int M, int N, int K) {
  __shared__ float As[32][68];  // [k][m], pad 68 keeps float4 alignment + low conflicts
  __shared__ float Ws[32][68];  // [k][n]
  const int tid = threadIdx.x;
  const int tx = tid & 15, ty = tid >> 4;
  const int mbase = blockIdx.y << 6, nbase = blockIdx.x << 6;
  float c[4][4] = {};
  const int lrow = tid >> 2;         // 0..63
  const int lkk  = (tid & 3) << 3;   // 0,8,16,24
  const float* Ap = A + (size_t)(mbase + lrow) * K + lkk;
  const float* Wp = W + (size_t)(nbase + lrow) * K + lkk;

  for (int k0 = 0; k0 < K; k0 += 32) {
    float4 a0 = *(const float4*)Ap;
    float4 a1 = *(const float4*)(Ap + 4);
    float4 w0 = *(const float4*)Wp;
    float4 w1 = *(const float4*)(Wp + 4);
    Ap += 32; Wp += 32;
    __syncthreads();
    As[lkk + 0][lrow] = a0.x; As[lkk + 1][lrow] = a0.y;
    As[lkk + 2][lrow] = a0.z; As[lkk + 3][lrow] = a0.w;
    As[lkk + 4][lrow] = a1.x; As[lkk + 5][lrow] = a1.y;
    As[lkk + 6][lrow] = a1.z; As[lkk + 7][lrow] = a1.w;
    Ws[lkk + 0][lrow] = w0.x; Ws[lkk + 1][lrow] = w0.y;
    Ws[lkk + 2][lrow] = w0.z; Ws[lkk + 3][lrow] = w0.w;
    Ws[lkk + 4][lrow] = w1.x; Ws[lkk + 5][lrow] = w1.y;
    Ws[lkk + 6][lrow] = w1.z; Ws[lkk + 7][lrow] = w1.w;
    __syncthreads();
    #pragma unroll
    for (int k = 0; k < 32; k++) {
      const float4 a4 = *(const float4*)&As[k][ty << 2];
      const float4 b4 = *(const float4*)&Ws[k][tx << 2];
      c[0][0] += a4.x * b4.x; c[0][1] += a4.x * b4.y; c[0][2] += a4.x * b4.z; c[0][3] += a4.x * b4.w;
      c[1][0] += a4.y * b4.x; c[1][1] += a4.y * b4.y; c[1][2] += a4.y * b4.z; c[1][3] += a4.y * b4.w;
      c[2][0] += a4.z * b4.x; c[2][1] += a4.z * b4.y; c[2][2] += a4.z * b4.z; c[2][3] += a4.z * b4.w;
      c[3][0] += a4.w * b4.x; c[3][1] += a4.w * b4.y; c[3][2] += a4.w * b4.z; c[3][3] += a4.w * b4.w;
    }
  }

  const float scale = *scale_ptr;
  #pragma unroll
  for (int i = 0; i < 4; i++) {
    float* cp = Co + (size_t)(mbase + (ty << 2) + i) * N + nbase + (tx << 2);
    float4 o;
    o.x = c[i][0] * scale; o.y = c[i][1] * scale;
    o.z = c[i][2] * scale; o.w = c[i][3] * scale;
    *(float4*)cp = o;
  }
}

// ---------------- RoPE (in-place on q,k sections of qkv) ----------------
// One thread owns the pair (d, d+32) -> no in-place race.

__global__ void rope_kernel(float* qkv,
                            const float* __restrict__ cosp,
                            const float* __restrict__ sinp) {
  int i = blockIdx.x * blockDim.x + threadIdx.x;  // 0 .. 2*M_*512-1
  int which = i >> 21;                            // M_*512 = 2^21: 0=q, 1=k
  int rem = i & 2097151;
  int row = rem >> 9;                             // 0..4095
  int cp = rem & 511;
  int h = cp >> 5, p = cp & 31;
  int t = row & (T_ - 1);
  size_t base = (size_t)row * N3C + which * C_ + h * D_;
  float x1 = qkv[base + p];
  float x2 = qkv[base + p + 32];
  float c1 = cosp[t * 64 + p];
  float c2 = cosp[t * 64 + p + 32];
  float s1 = sinp[t * 64 + p];
  float s2 = sinp[t * 64 + p + 32];
  qkv[base + p]      = x1 * c1 - x2 * s1;
  qkv[base + p + 32] = x2 * c2 + x1 * s2;
}

// ---------------- causal flash attention ----------------
// block = 128 threads (2 waves), BQ=128 q-rows (1 per thread), BK=32 K/V tile in LDS.

#define BQ 128
#define BKT 32

__global__ __launch_bounds__(128) void flash_attn(const float* __restrict__ qkv,
                                                  float* __restrict__ y) {
  __shared__ float Kt[BKT][68];
  __shared__ float Vt[BKT][68];
  const int tid = threadIdx.x;
  const int qt = gridDim.x - 1 - blockIdx.x;   // big q-tiles dispatched first
  const int bh = blockIdx.y;
  const int b = bh >> 4, h = bh & 15;
  const int qrow = qt * BQ + tid;
  const size_t grow = (size_t)(b * T_ + qrow);
  const float* qp = qkv + grow * N3C + h * D_;

  float q[64], O[64], sreg[BKT];
  #pragma unroll
  for (int d = 0; d < 64; d++) { q[d] = 0.125f * qp[d]; O[d] = 0.f; }
  float m = -INFINITY, l = 0.f;

  const int ktmax = (qt * BQ + BQ - 1) >> 5;
  const float* kbase_ptr = qkv + (size_t)(b * T_) * N3C + C_ + h * D_;

  for (int kt = 0; kt <= ktmax; kt++) {
    const int kb = kt * BKT;
    __syncthreads();
    #pragma unroll
    for (int i = 0; i < 16; i++) {
      int row = i * 2 + (tid >> 6);
      int col = tid & 63;
      const float* kp = kbase_ptr + (size_t)(kb + row) * N3C + col;
      Kt[row][col] = kp[0];
      Vt[row][col] = kp[C_];
    }
    __syncthreads();

    float smax = -INFINITY;
    #pragma unroll
    for (int j = 0; j < BKT; j++) {
      float a0 = 0.f, a1 = 0.f, a2 = 0.f, a3 = 0.f;
      #pragma unroll
      for (int d = 0; d < 64; d += 4) {
        a0 += q[d]     * Kt[j][d];
        a1 += q[d + 1] * Kt[j][d + 1];
        a2 += q[d + 2] * Kt[j][d + 2];
        a3 += q[d + 3] * Kt[j][d + 3];
      }
      float acc = (a0 + a1) + (a2 + a3);
      acc = (kb + j <= qrow) ? acc : -INFINITY;
      sreg[j] = acc;
      smax = fmaxf(smax, acc);
    }

    float mnew = fmaxf(m, smax);
    float alpha = __expf(m - mnew);     // exp(-inf)=0 on first tile (m=-inf, mnew finite)
    float psum = 0.f;
    #pragma unroll
    for (int j = 0; j < BKT; j++) {
      float p = __expf(sreg[j] - mnew); // masked: exp(-inf)=0
      sreg[j] = p; psum += p;
    }
    l = l * alpha + psum;
    m = mnew;
    #pragma unroll
    for (int d = 0; d < 64; d++) O[d] *= alpha;
    #pragma unroll
    for (int j = 0; j < BKT; j++) {
      const float p = sreg[j];
      #pragma unroll
      for (int d = 0; d < 64; d++) O[d] += p * Vt[j][d];
    }
  }

  const float inv = 1.0f / l;
  float* yp = y + grow * C_ + h * D_;
  #pragma unroll
  for (int d = 0; d < 64; d += 4) {
    float4 o;
    o.x = O[d] * inv; o.y = O[d + 1] * inv;
    o.z = O[d + 2] * inv; o.w = O[d + 3] * inv;
    *(float4*)(yp + d) = o;
  }
}

// ---------------- launch ----------------

extern "C" void kernel_launch(void* const* d_in, const int* in_sizes, int n_in,
                              void* d_out, int out_size, void* d_ws, size_t ws_size,
                              hipStream_t stream) {
  (void)in_sizes; (void)n_in; (void)out_size; (void)ws_size;
  const float* x      = (const float*)d_in[0];
  const float* cosp   = (const float*)d_in[1];
  const float* sinp   = (const float*)d_in[2];
  const float* w_qkv  = (const float*)d_in[3];
  const float* w_proj = (const float*)d_in[4];
  float* out = (float*)d_out;

  char* ws = (char*)d_ws;
  double* sums = (double*)ws;                 // 2 doubles @ 0
  float*  ams  = (float*)(ws + 16);           // 2 floats  @ 16
  float* tern_qkv  = (float*)(ws + 256);             // 3072*1024 fp32 (12 MB)
  float* tern_proj = tern_qkv + 3 * C_ * C_;         // 1024*1024 fp32 (4 MB)
  float* qkv       = tern_proj + C_ * C_;            // 4096*3072 fp32 (48 MB)
  float* yb        = qkv + (size_t)M_ * N3C;         // 4096*1024 fp32 (16 MB)
  // total ws usage ~80 MB

  zero_sums<<<1, 64, 0, stream>>>(sums);
  abs_sum_kernel<<<1024, 256, 0, stream>>>(w_qkv, (3 * C_ * C_) / 4, sums + 0);
  abs_sum_kernel<<<512, 256, 0, stream>>>(w_proj, (C_ * C_) / 4, sums + 1);
  ternarize_kernel<<<(3 * C_ * C_) / 256, 256, 0, stream>>>(w_qkv, tern_qkv, 3 * C_ * C_,
                                                            sums + 0, 1.0f / (3 * C_ * C_), ams + 0);
  ternarize_kernel<<<(C_ * C_) / 256, 256, 0, stream>>>(w_proj, tern_proj, C_ * C_,
                                                        sums + 1, 1.0f / (C_ * C_), ams + 1);
  gemm_bt<<<dim3(N3C / 64, M_ / 64), 256, 0, stream>>>(x, tern_qkv, ams + 0, qkv, M_, N3C, C_);
  rope_kernel<<<(2 * M_ * 512) / 256, 256, 0, stream>>>(qkv, cosp, sinp);
  flash_attn<<<dim3(T_ / BQ, B_ * H_), 128, 0, stream>>>(qkv, yb);
  gemm_bt<<<dim3(C_ / 64, M_ / 64), 256, 0, stream>>>(yb, tern_proj, ams + 1, out, M_, C_, C_);
}

// Round 3
// 605.278 us; speedup vs baseline: 4.9545x; 4.9545x over previous
//
#include <hip/hip_runtime.h>
#include <hip/hip_bf16.h>

// Problem constants: B=2, T=2048, C=1024, H=16, D=64
#define B_ 2
#define T_ 2048
#define C_ 1024
#define H_ 16
#define D_ 64
#define M_ 4096
#define N3C 3072

using short8  = __attribute__((ext_vector_type(8))) short;
using floatx4 = __attribute__((ext_vector_type(4))) float;

__device__ __forceinline__ unsigned short f2b(float f) {
  __hip_bfloat16 h = __float2bfloat16(f);
  return *reinterpret_cast<unsigned short*>(&h);
}
__device__ __forceinline__ float b2f(unsigned short u) {
  union { unsigned int i; float f; } x; x.i = ((unsigned int)u) << 16; return x.f;
}

// ---------------- ternarization ----------------

__global__ void zero_sums(double* sums) {
  if (threadIdx.x < 2) sums[threadIdx.x] = 0.0;
}

__global__ void abs_sum_kernel(const float* __restrict__ w, int n4, double* out) {
  int stride = gridDim.x * blockDim.x;
  double s = 0.0;
  for (int i = blockIdx.x * blockDim.x + threadIdx.x; i < n4; i += stride) {
    float4 v = ((const float4*)w)[i];
    s += (double)fabsf(v.x) + (double)fabsf(v.y) + (double)fabsf(v.z) + (double)fabsf(v.w);
  }
  #pragma unroll
  for (int off = 32; off > 0; off >>= 1)
    s += __shfl_down(s, off, 64);
  if ((threadIdx.x & 63) == 0) atomicAdd(out, s);
}

// exact {-1,0,+1} in bf16; abs_mean scale applied fp32 in GEMM epilogue
__global__ void ternarize_kernel(const float* __restrict__ w, unsigned short* __restrict__ out,
                                 int n, const double* sum, float inv_n, float* am_out) {
  float am = fmaxf((float)(*sum) * inv_n, 1e-5f);
  int i = blockIdx.x * blockDim.x + threadIdx.x;
  if (i == 0) *am_out = am;
  if (i < n) {
    float thr = 0.7f * am;
    float x = w[i];
    out[i] = (x > thr) ? 0x3F80u : ((x < -thr) ? 0xBF80u : 0u);
  }
}

__global__ void cvt_f32_bf16(const float* __restrict__ in, unsigned short* __restrict__ out, int n4) {
  int i = blockIdx.x * blockDim.x + threadIdx.x;
  if (i < n4) {
    float4 v = ((const float4*)in)[i];
    ushort4 o; o.x = f2b(v.x); o.y = f2b(v.y); o.z = f2b(v.z); o.w = f2b(v.w);
    ((ushort4*)out)[i] = o;
  }
}

// ---------------- MFMA GEMM: C[M,N] = (A[M,K] @ W[N,K]^T) * scale ----------------
// Wave strip 32x64, block = 4 waves stacked along M (128x64 per block). No LDS.

template<int OUT_BF16>
__global__ __launch_bounds__(256) void mfma_gemm_bt(const unsigned short* __restrict__ A,
                                                    const unsigned short* __restrict__ W,
                                                    const float* __restrict__ scale_ptr,
                                                    void* __restrict__ Cout,
                                                    int M, int N, int K) {
  const int lane = threadIdx.x & 63;
  const int wv = threadIdx.x >> 6;
  const int m = lane & 15, g = lane >> 4;
  const int m0 = blockIdx.y * 128 + wv * 32;
  const int n0 = blockIdx.x * 64;

  const unsigned short* a0p = A + (size_t)(m0 + m) * K + g * 8;
  const unsigned short* a1p = a0p + (size_t)16 * K;
  const unsigned short* wp  = W + (size_t)(n0 + m) * K + g * 8;
  const size_t wstep = (size_t)16 * K;

  floatx4 acc[2][4] = {};
  for (int kc = 0; kc < K; kc += 32) {
    short8 a0 = *(const short8*)a0p;
    short8 a1 = *(const short8*)a1p;
    short8 b0 = *(const short8*)wp;
    short8 b1 = *(const short8*)(wp + wstep);
    short8 b2 = *(const short8*)(wp + 2 * wstep);
    short8 b3 = *(const short8*)(wp + 3 * wstep);
    a0p += 32; a1p += 32; wp += 32;
    acc[0][0] = __builtin_amdgcn_mfma_f32_16x16x32_bf16(a0, b0, acc[0][0], 0, 0, 0);
    acc[0][1] = __builtin_amdgcn_mfma_f32_16x16x32_bf16(a0, b1, acc[0][1], 0, 0, 0);
    acc[0][2] = __builtin_amdgcn_mfma_f32_16x16x32_bf16(a0, b2, acc[0][2], 0, 0, 0);
    acc[0][3] = __builtin_amdgcn_mfma_f32_16x16x32_bf16(a0, b3, acc[0][3], 0, 0, 0);
    acc[1][0] = __builtin_amdgcn_mfma_f32_16x16x32_bf16(a1, b0, acc[1][0], 0, 0, 0);
    acc[1][1] = __builtin_amdgcn_mfma_f32_16x16x32_bf16(a1, b1, acc[1][1], 0, 0, 0);
    acc[1][2] = __builtin_amdgcn_mfma_f32_16x16x32_bf16(a1, b2, acc[1][2], 0, 0, 0);
    acc[1][3] = __builtin_amdgcn_mfma_f32_16x16x32_bf16(a1, b3, acc[1][3], 0, 0, 0);
  }

  const float scale = *scale_ptr;
  #pragma unroll
  for (int i = 0; i < 2; i++)
    #pragma unroll
    for (int nt = 0; nt < 4; nt++)
      #pragma unroll
      for (int r = 0; r < 4; r++) {
        int row = m0 + i * 16 + g * 4 + r;
        int col = n0 + nt * 16 + m;
        float val = acc[i][nt][r] * scale;
        if (OUT_BF16) ((unsigned short*)Cout)[(size_t)row * N + col] = f2b(val);
        else          ((float*)Cout)[(size_t)row * N + col] = val;
      }
}

// ---------------- RoPE + pack Q,K -> [bh][t][d] bf16 (q pre-scaled by 1/8) ----------------

__global__ void rope_pack(const unsigned short* __restrict__ qkv,  // bf16 [4096][3072]
                          const float* __restrict__ cosp, const float* __restrict__ sinp,
                          unsigned short* __restrict__ Qb, unsigned short* __restrict__ Kb) {
  int i = blockIdx.x * blockDim.x + threadIdx.x;  // 0 .. M_*512-1
  int row = i >> 9;                               // b*T+t
  int cp = i & 511;
  int h = cp >> 5, p = cp & 31;
  int t = row & (T_ - 1);
  int b = row >> 11;
  int bh = b * H_ + h;
  size_t qb = (size_t)row * N3C + h * 64;
  float q1 = b2f(qkv[qb + p]),      q2 = b2f(qkv[qb + p + 32]);
  float k1 = b2f(qkv[qb + C_ + p]), k2 = b2f(qkv[qb + C_ + p + 32]);
  float c1 = cosp[t * 64 + p], c2 = cosp[t * 64 + p + 32];
  float s1 = sinp[t * 64 + p], s2 = sinp[t * 64 + p + 32];
  size_t ob = (size_t)bh * T_ * 64 + (size_t)t * 64;
  Qb[ob + p]      = f2b((q1 * c1 - q2 * s1) * 0.125f);
  Qb[ob + p + 32] = f2b((q2 * c2 + q1 * s2) * 0.125f);
  Kb[ob + p]      = f2b(k1 * c1 - k2 * s1);
  Kb[ob + p + 32] = f2b(k2 * c2 + k1 * s2);
}

// ---------------- V transpose -> Vtb[bh][d][t] bf16 ----------------

__global__ __launch_bounds__(256) void v_transpose(const unsigned short* __restrict__ qkv,
                                                   unsigned short* __restrict__ Vtb) {
  __shared__ unsigned short L[64][65];
  int bh = blockIdx.y;
  int t0 = blockIdx.x * 64;
  int b = bh >> 4, h = bh & 15;
  #pragma unroll
  for (int it = 0; it < 16; it++) {
    int idx = it * 256 + threadIdx.x;
    int tl = idx >> 6, d = idx & 63;
    L[tl][d] = qkv[(size_t)(b * T_ + t0 + tl) * N3C + 2 * C_ + h * 64 + d];
  }
  __syncthreads();
  #pragma unroll
  for (int it = 0; it < 16; it++) {
    int idx = it * 256 + threadIdx.x;
    int dr = idx >> 6, tl = idx & 63;
    Vtb[(size_t)bh * 64 * T_ + (size_t)dr * T_ + t0 + tl] = L[tl][dr];
  }
}

// ---------------- MFMA flash attention ----------------
// One wave owns 16 q-rows. S^T = K·Q^T (per-lane scalar softmax state),
// P^T (C-layout) -> LDS (8B writes) -> A-layout (16B reads) -> P·V.
// No __syncthreads anywhere; Plds is per-wave private.

__global__ __launch_bounds__(256) void flash_mfma(const unsigned short* __restrict__ Qb,
                                                  const unsigned short* __restrict__ Kb,
                                                  const unsigned short* __restrict__ Vtb,
                                                  unsigned short* __restrict__ Y) {
  __shared__ __align__(16) unsigned short Plds[4][16][72];  // row stride 144B (16B-mult)
  const int lane = threadIdx.x & 63;
  const int wv = threadIdx.x >> 6;
  const int m = lane & 15, g = lane >> 4;
  const int bh = blockIdx.y;
  const int qt4 = gridDim.x - 1 - blockIdx.x;   // long strips dispatched first
  const int qbase = qt4 * 64 + wv * 16;
  const size_t hb = (size_t)bh * T_ * 64;

  const unsigned short* qp = Qb + hb + (size_t)(qbase + m) * 64 + g * 8;
  short8 qf0 = *(const short8*)qp;
  short8 qf1 = *(const short8*)(qp + 32);

  floatx4 O[4] = {};
  float mrun = -INFINITY, lrun = 0.f;
  const int q_glob = qbase + m;
  const int ktmax = (qbase + 15) >> 6;

  for (int kt = 0; kt <= ktmax; kt++) {
    const int kb = kt * 64;
    const unsigned short* kp = Kb + hb + (size_t)(kb + m) * 64 + g * 8;
    floatx4 S[4];
    #pragma unroll
    for (int mt = 0; mt < 4; mt++) {
      short8 kf0 = *(const short8*)(kp + mt * 16 * 64);
      short8 kf1 = *(const short8*)(kp + mt * 16 * 64 + 32);
      floatx4 s = {};
      s = __builtin_amdgcn_mfma_f32_16x16x32_bf16(kf0, qf0, s, 0, 0, 0);
      s = __builtin_amdgcn_mfma_f32_16x16x32_bf16(kf1, qf1, s, 0, 0, 0);
      S[mt] = s;
    }
    // causal mask + per-q max (each lane: all 16 values share q = q_glob)
    float mx = -INFINITY;
    #pragma unroll
    for (int mt = 0; mt < 4; mt++)
      #pragma unroll
      for (int r = 0; r < 4; r++) {
        int kg = kb + mt * 16 + g * 4 + r;
        float v = (kg <= q_glob) ? S[mt][r] : -INFINITY;
        S[mt][r] = v;
        mx = fmaxf(mx, v);
      }
    mx = fmaxf(mx, __shfl_xor(mx, 16, 64));
    mx = fmaxf(mx, __shfl_xor(mx, 32, 64));
    float mnew = fmaxf(mrun, mx);
    float alpha = __expf(mrun - mnew);  // first tile: exp(-inf)=0
    float ps = 0.f;
    #pragma unroll
    for (int mt = 0; mt < 4; mt++) {
      float e0 = __expf(S[mt][0] - mnew);
      float e1 = __expf(S[mt][1] - mnew);
      float e2 = __expf(S[mt][2] - mnew);
      float e3 = __expf(S[mt][3] - mnew);
      ps += (e0 + e1) + (e2 + e3);
      ushort4 o; o.x = f2b(e0); o.y = f2b(e1); o.z = f2b(e2); o.w = f2b(e3);
      *(ushort4*)&Plds[wv][m][mt * 16 + g * 4] = o;   // P[q=m][k=mt*16+g*4 ..+3]
    }
    ps += __shfl_xor(ps, 16, 64);
    ps += __shfl_xor(ps, 32, 64);
    lrun = lrun * alpha + ps;
    mrun = mnew;

    // rescale O: O C-layout rows are q_local = g*4+r; alpha lives at lane q
    float al[4];
    #pragma unroll
    for (int r = 0; r < 4; r++) al[r] = __shfl(alpha, g * 4 + r, 64);
    #pragma unroll
    for (int nt = 0; nt < 4; nt++)
      #pragma unroll
      for (int r = 0; r < 4; r++) O[nt][r] *= al[r];

    // P (A-layout) from LDS; V (B-operand) direct from Vtb
    short8 pa0 = *(const short8*)&Plds[wv][m][g * 8];
    short8 pa1 = *(const short8*)&Plds[wv][m][32 + g * 8];
    const unsigned short* vp = Vtb + (size_t)bh * 64 * T_ + (size_t)m * T_ + kb + g * 8;
    #pragma unroll
    for (int nt = 0; nt < 4; nt++) {
      short8 v0 = *(const short8*)(vp + (size_t)nt * 16 * T_);
      short8 v1 = *(const short8*)(vp + (size_t)nt * 16 * T_ + 32);
      O[nt] = __builtin_amdgcn_mfma_f32_16x16x32_bf16(pa0, v0, O[nt], 0, 0, 0);
      O[nt] = __builtin_amdgcn_mfma_f32_16x16x32_bf16(pa1, v1, O[nt], 0, 0, 0);
    }
  }

  float li[4];
  #pragma unroll
  for (int r = 0; r < 4; r++) li[r] = 1.0f / __shfl(lrun, g * 4 + r, 64);
  const int b = bh >> 4, h = bh & 15;
  #pragma unroll
  for (int nt = 0; nt < 4; nt++)
    #pragma unroll
    for (int r = 0; r < 4; r++) {
      int trow = qbase + g * 4 + r;
      int col = h * 64 + nt * 16 + m;
      Y[(size_t)(b * T_ + trow) * C_ + col] = f2b(O[nt][r] * li[r]);
    }
}

// ---------------- launch ----------------

extern "C" void kernel_launch(void* const* d_in, const int* in_sizes, int n_in,
                              void* d_out, int out_size, void* d_ws, size_t ws_size,
                              hipStream_t stream) {
  (void)in_sizes; (void)n_in; (void)out_size; (void)ws_size;
  const float* x      = (const float*)d_in[0];
  const float* cosp   = (const float*)d_in[1];
  const float* sinp   = (const float*)d_in[2];
  const float* w_qkv  = (const float*)d_in[3];
  const float* w_proj = (const float*)d_in[4];
  float* out = (float*)d_out;

  char* ws = (char*)d_ws;
  double* sums = (double*)ws;                       // 16 B
  float*  ams  = (float*)(ws + 16);                 // 8 B
  unsigned short* wqkv_b  = (unsigned short*)(ws + 256);            // 6 MB
  unsigned short* wproj_b = wqkv_b + (size_t)N3C * C_;              // 2 MB
  unsigned short* xb      = wproj_b + (size_t)C_ * C_;              // 8 MB
  unsigned short* qkv_b   = xb + (size_t)M_ * C_;                   // 24 MB
  unsigned short* Qb      = qkv_b + (size_t)M_ * N3C;               // 8 MB
  unsigned short* Kb      = Qb + (size_t)M_ * D_ * 1;               // wait: Qb is [32][2048][64] = M_*64
  // (Qb/Kb/Vtb are B*H*T*D = 2*16*2048*64 = 4M elems = 8MB each)
  Kb = Qb + (size_t)B_ * H_ * T_ * D_;
  unsigned short* Vtb = Kb + (size_t)B_ * H_ * T_ * D_;
  unsigned short* yb  = Vtb + (size_t)B_ * H_ * T_ * D_;            // [4096][1024] bf16, 8 MB

  zero_sums<<<1, 64, 0, stream>>>(sums);
  abs_sum_kernel<<<1024, 256, 0, stream>>>(w_qkv, (3 * C_ * C_) / 4, sums + 0);
  abs_sum_kernel<<<512, 256, 0, stream>>>(w_proj, (C_ * C_) / 4, sums + 1);
  ternarize_kernel<<<(3 * C_ * C_) / 256, 256, 0, stream>>>(w_qkv, wqkv_b, 3 * C_ * C_,
                                                            sums + 0, 1.0f / (3 * C_ * C_), ams + 0);
  ternarize_kernel<<<(C_ * C_) / 256, 256, 0, stream>>>(w_proj, wproj_b, C_ * C_,
                                                        sums + 1, 1.0f / (C_ * C_), ams + 1);
  cvt_f32_bf16<<<(M_ * C_ / 4 + 255) / 256, 256, 0, stream>>>(x, xb, M_ * C_ / 4);
  mfma_gemm_bt<1><<<dim3(N3C / 64, M_ / 128), 256, 0, stream>>>(xb, wqkv_b, ams + 0,
                                                                qkv_b, M_, N3C, C_);
  rope_pack<<<(M_ * 512) / 256, 256, 0, stream>>>(qkv_b, cosp, sinp, Qb, Kb);
  v_transpose<<<dim3(T_ / 64, B_ * H_), 256, 0, stream>>>(qkv_b, Vtb);
  flash_mfma<<<dim3(T_ / 64, B_ * H_), 256, 0, stream>>>(Qb, Kb, Vtb, yb);
  mfma_gemm_bt<0><<<dim3(C_ / 64, M_ / 128), 256, 0, stream>>>(yb, wproj_b, ams + 1,
                                                               out, M_, C_, C_);
}

// Round 4
// 467.348 us; speedup vs baseline: 6.4168x; 1.2951x over previous
//
#include <hip/hip_runtime.h>
#include <hip/hip_bf16.h>

// Problem constants: B=2, T=2048, C=1024, H=16, D=64
#define B_ 2
#define T_ 2048
#define C_ 1024
#define H_ 16
#define D_ 64
#define M_ 4096
#define N3C 3072

using short8  = __attribute__((ext_vector_type(8))) short;
using floatx4 = __attribute__((ext_vector_type(4))) float;
typedef unsigned int u32;

__device__ __forceinline__ unsigned short f2b(float f) {
  __hip_bfloat16 h = __float2bfloat16(f);
  return *reinterpret_cast<unsigned short*>(&h);
}
__device__ __forceinline__ float b2f(unsigned short u) {
  union { unsigned int i; float f; } x; x.i = ((unsigned int)u) << 16; return x.f;
}

// async global->LDS, 16B per lane; LDS dest = uniform base + lane*16
__device__ __forceinline__ void gll16(const void* g, void* l) {
  __builtin_amdgcn_global_load_lds((const __attribute__((address_space(1))) u32*)g,
                                   (__attribute__((address_space(3))) u32*)l, 16, 0, 0);
}

// ---------------- ternarization ----------------

__global__ void zero_sums(double* sums) {
  if (threadIdx.x < 2) sums[threadIdx.x] = 0.0;
}

__global__ void abs_sum_kernel(const float* __restrict__ w, int n4, double* out) {
  int stride = gridDim.x * blockDim.x;
  double s = 0.0;
  for (int i = blockIdx.x * blockDim.x + threadIdx.x; i < n4; i += stride) {
    float4 v = ((const float4*)w)[i];
    s += (double)fabsf(v.x) + (double)fabsf(v.y) + (double)fabsf(v.z) + (double)fabsf(v.w);
  }
  #pragma unroll
  for (int off = 32; off > 0; off >>= 1)
    s += __shfl_down(s, off, 64);
  if ((threadIdx.x & 63) == 0) atomicAdd(out, s);
}

// exact {-1,0,+1} in bf16; abs_mean applied fp32 in GEMM epilogue
__global__ void ternarize_kernel(const float* __restrict__ w, unsigned short* __restrict__ out,
                                 int n, const double* sum, float inv_n, float* am_out) {
  float am = fmaxf((float)(*sum) * inv_n, 1e-5f);
  int i = blockIdx.x * blockDim.x + threadIdx.x;
  if (i == 0) *am_out = am;
  if (i < n) {
    float thr = 0.7f * am;
    float x = w[i];
    out[i] = (x > thr) ? 0x3F80u : ((x < -thr) ? 0xBF80u : 0u);
  }
}

__global__ void cvt_f32_bf16(const float* __restrict__ in, unsigned short* __restrict__ out, int n4) {
  int i = blockIdx.x * blockDim.x + threadIdx.x;
  if (i < n4) {
    float4 v = ((const float4*)in)[i];
    ushort4 o; o.x = f2b(v.x); o.y = f2b(v.y); o.z = f2b(v.z); o.w = f2b(v.w);
    ((ushort4*)out)[i] = o;
  }
}

// ---------------- m97-style MFMA GEMM: C[M,N] = (A[M,K] @ W[N,K]^T) * scale ----
// 128x128 tile, BK=32, 256 threads (2x2 waves of 64x64), global_load_lds staging.

template<int OUT_BF16>
__global__ __launch_bounds__(256) void gemm128(const unsigned short* __restrict__ A,
                                               const unsigned short* __restrict__ W,
                                               const float* __restrict__ scale_ptr,
                                               void* __restrict__ Cout,
                                               int N, int K) {
  __shared__ __attribute__((aligned(16))) unsigned short As[128 * 32];
  __shared__ __attribute__((aligned(16))) unsigned short Ws[128 * 32];
  const int tid = threadIdx.x, lane = tid & 63, wv = tid >> 6;
  const int m = lane & 15, g = lane >> 4;
  const int m0 = blockIdx.y * 128, n0 = blockIdx.x * 128;
  const int wm = (wv >> 1) * 64, wn = (wv & 1) * 64;

  // staging: wave wv stages rows [wv*16, wv*16+15] and [64+wv*16, ...] of both tiles
  const int srow = wv * 16 + (lane >> 2);
  const int skoff = (lane & 3) * 8;
  const unsigned short* ga0 = A + (size_t)(m0 + srow) * K + skoff;
  const unsigned short* ga1 = A + (size_t)(m0 + 64 + srow) * K + skoff;
  const unsigned short* gw0 = W + (size_t)(n0 + srow) * K + skoff;
  const unsigned short* gw1 = W + (size_t)(n0 + 64 + srow) * K + skoff;
  unsigned short* la0 = As + (wv * 16) * 32;        // wave-uniform LDS bases
  unsigned short* la1 = As + (64 + wv * 16) * 32;
  unsigned short* lw0 = Ws + (wv * 16) * 32;
  unsigned short* lw1 = Ws + (64 + wv * 16) * 32;

  floatx4 acc[4][4] = {};
  for (int kc = 0; kc < K; kc += 32) {
    __syncthreads();                // previous iteration's readers done
    gll16(ga0, la0); gll16(ga1, la1); gll16(gw0, lw0); gll16(gw1, lw1);
    ga0 += 32; ga1 += 32; gw0 += 32; gw1 += 32;
    __syncthreads();                // staging complete (vmcnt(0) drained)
    short8 af[4], wf[4];
    #pragma unroll
    for (int r = 0; r < 4; r++)
      af[r] = *(const short8*)&As[(wm + r * 16 + m) * 32 + g * 8];
    #pragma unroll
    for (int c = 0; c < 4; c++)
      wf[c] = *(const short8*)&Ws[(wn + c * 16 + m) * 32 + g * 8];
    #pragma unroll
    for (int r = 0; r < 4; r++)
      #pragma unroll
      for (int c = 0; c < 4; c++)
        acc[r][c] = __builtin_amdgcn_mfma_f32_16x16x32_bf16(af[r], wf[c], acc[r][c], 0, 0, 0);
  }

  const float scale = *scale_ptr;
  #pragma unroll
  for (int r = 0; r < 4; r++)
    #pragma unroll
    for (int c = 0; c < 4; c++)
      #pragma unroll
      for (int i = 0; i < 4; i++) {
        int row = m0 + wm + r * 16 + g * 4 + i;
        int col = n0 + wn + c * 16 + m;
        float val = acc[r][c][i] * scale;
        if (OUT_BF16) ((unsigned short*)Cout)[(size_t)row * N + col] = f2b(val);
        else          ((float*)Cout)[(size_t)row * N + col] = val;
      }
}

// ---------------- RoPE + pack Q,K -> [bh][t][d] bf16 (Q pre-scaled by log2e/8) ----

__global__ void rope_pack(const unsigned short* __restrict__ qkv,  // bf16 [4096][3072]
                          const float* __restrict__ cosp, const float* __restrict__ sinp,
                          unsigned short* __restrict__ Qb, unsigned short* __restrict__ Kb) {
  const float QSC = 0.125f * 1.44269504088896340736f;   // (1/sqrt(D)) * log2(e)
  int i = blockIdx.x * blockDim.x + threadIdx.x;  // 0 .. M_*512-1
  int row = i >> 9;                               // b*T+t
  int cp = i & 511;
  int h = cp >> 5, p = cp & 31;
  int t = row & (T_ - 1);
  int b = row >> 11;
  int bh = b * H_ + h;
  size_t qb = (size_t)row * N3C + h * 64;
  float q1 = b2f(qkv[qb + p]),      q2 = b2f(qkv[qb + p + 32]);
  float k1 = b2f(qkv[qb + C_ + p]), k2 = b2f(qkv[qb + C_ + p + 32]);
  float c1 = cosp[t * 64 + p], c2 = cosp[t * 64 + p + 32];
  float s1 = sinp[t * 64 + p], s2 = sinp[t * 64 + p + 32];
  size_t ob = (size_t)bh * T_ * 64 + (size_t)t * 64;
  Qb[ob + p]      = f2b((q1 * c1 - q2 * s1) * QSC);
  Qb[ob + p + 32] = f2b((q2 * c2 + q1 * s2) * QSC);
  Kb[ob + p]      = f2b(k1 * c1 - k2 * s1);
  Kb[ob + p + 32] = f2b(k2 * c2 + k1 * s2);
}

// ---------------- V transpose -> Vtb[bh][d][t] bf16 ----------------

__global__ __launch_bounds__(256) void v_transpose(const unsigned short* __restrict__ qkv,
                                                   unsigned short* __restrict__ Vtb) {
  __shared__ unsigned short L[64][65];
  int bh = blockIdx.y;
  int t0 = blockIdx.x * 64;
  int b = bh >> 4, h = bh & 15;
  #pragma unroll
  for (int it = 0; it < 16; it++) {
    int idx = it * 256 + threadIdx.x;
    int tl = idx >> 6, d = idx & 63;
    L[tl][d] = qkv[(size_t)(b * T_ + t0 + tl) * N3C + 2 * C_ + h * 64 + d];
  }
  __syncthreads();
  #pragma unroll
  for (int it = 0; it < 16; it++) {
    int idx = it * 256 + threadIdx.x;
    int dr = idx >> 6, tl = idx & 63;
    Vtb[(size_t)bh * 64 * T_ + (size_t)dr * T_ + t0 + tl] = L[tl][dr];
  }
}

// ---------------- MFMA flash attention, m=0 softmax (no online max) ----------
// One wave owns 16 q-rows. S^T = K*Q^T; P^T C-layout -> LDS -> A-layout -> P*V.
// Full tiles unmasked; single diagonal tile masked. K prefetched 1 tile ahead.

__global__ __launch_bounds__(256) void flash_mfma(const unsigned short* __restrict__ Qb,
                                                  const unsigned short* __restrict__ Kb,
                                                  const unsigned short* __restrict__ Vtb,
                                                  unsigned short* __restrict__ Y) {
  __shared__ __align__(16) unsigned short Plds[4][16][72];  // row stride 144B
  const int lane = threadIdx.x & 63;
  const int wv = threadIdx.x >> 6;
  const int m = lane & 15, g = lane >> 4;
  const int bh = blockIdx.y;
  const int qt4 = gridDim.x - 1 - blockIdx.x;   // long strips dispatched first
  const int qbase = qt4 * 64 + wv * 16;
  const size_t hb = (size_t)bh * T_ * 64;

  const unsigned short* qp = Qb + hb + (size_t)(qbase + m) * 64 + g * 8;
  short8 qf0 = *(const short8*)qp;
  short8 qf1 = *(const short8*)(qp + 32);

  floatx4 O[4] = {};
  float lsum = 0.f;
  const int q_glob = qbase + m;
  const int nfull = qbase >> 6;       // tiles with all 64 keys <= every q in strip

  const unsigned short* kp0 = Kb + hb + (size_t)m * 64 + g * 8;
  const unsigned short* vp0 = Vtb + (size_t)bh * 64 * T_ + (size_t)m * T_ + g * 8;

  // prefetch K tile 0
  short8 kf[8];
  #pragma unroll
  for (int mt = 0; mt < 4; mt++) {
    kf[2 * mt]     = *(const short8*)(kp0 + (size_t)mt * 16 * 64);
    kf[2 * mt + 1] = *(const short8*)(kp0 + (size_t)mt * 16 * 64 + 32);
  }

  for (int kt = 0; kt < nfull; kt++) {
    const int kb = kt * 64;
    // V loads for this tile (used at the end)
    short8 vf[8];
    const unsigned short* vp = vp0 + kb;
    #pragma unroll
    for (int nt = 0; nt < 4; nt++) {
      vf[2 * nt]     = *(const short8*)(vp + (size_t)nt * 16 * T_);
      vf[2 * nt + 1] = *(const short8*)(vp + (size_t)nt * 16 * T_ + 32);
    }
    // QK^T on prefetched K
    floatx4 S[4];
    #pragma unroll
    for (int mt = 0; mt < 4; mt++) {
      floatx4 s = {};
      s = __builtin_amdgcn_mfma_f32_16x16x32_bf16(kf[2 * mt], qf0, s, 0, 0, 0);
      s = __builtin_amdgcn_mfma_f32_16x16x32_bf16(kf[2 * mt + 1], qf1, s, 0, 0, 0);
      S[mt] = s;
    }
    // prefetch next K tile
    const unsigned short* kpn = kp0 + (size_t)(kb + 64) * 64;
    #pragma unroll
    for (int mt = 0; mt < 4; mt++) {
      kf[2 * mt]     = *(const short8*)(kpn + (size_t)mt * 16 * 64);
      kf[2 * mt + 1] = *(const short8*)(kpn + (size_t)mt * 16 * 64 + 32);
    }
    // p = exp2(s) (log2e folded into Q); no mask, no max
    #pragma unroll
    for (int mt = 0; mt < 4; mt++) {
      float e0 = exp2f(S[mt][0]);
      float e1 = exp2f(S[mt][1]);
      float e2 = exp2f(S[mt][2]);
      float e3 = exp2f(S[mt][3]);
      lsum += (e0 + e1) + (e2 + e3);
      ushort4 o; o.x = f2b(e0); o.y = f2b(e1); o.z = f2b(e2); o.w = f2b(e3);
      *(ushort4*)&Plds[wv][m][mt * 16 + g * 4] = o;
    }
    short8 pa0 = *(const short8*)&Plds[wv][m][g * 8];
    short8 pa1 = *(const short8*)&Plds[wv][m][32 + g * 8];
    #pragma unroll
    for (int nt = 0; nt < 4; nt++) {
      O[nt] = __builtin_amdgcn_mfma_f32_16x16x32_bf16(pa0, vf[2 * nt], O[nt], 0, 0, 0);
      O[nt] = __builtin_amdgcn_mfma_f32_16x16x32_bf16(pa1, vf[2 * nt + 1], O[nt], 0, 0, 0);
    }
  }

  // diagonal (masked) tile: kb = nfull*64, fragments already in kf
  {
    const int kb = nfull * 64;
    short8 vf[8];
    const unsigned short* vp = vp0 + kb;
    #pragma unroll
    for (int nt = 0; nt < 4; nt++) {
      vf[2 * nt]     = *(const short8*)(vp + (size_t)nt * 16 * T_);
      vf[2 * nt + 1] = *(const short8*)(vp + (size_t)nt * 16 * T_ + 32);
    }
    floatx4 S[4];
    #pragma unroll
    for (int mt = 0; mt < 4; mt++) {
      floatx4 s = {};
      s = __builtin_amdgcn_mfma_f32_16x16x32_bf16(kf[2 * mt], qf0, s, 0, 0, 0);
      s = __builtin_amdgcn_mfma_f32_16x16x32_bf16(kf[2 * mt + 1], qf1, s, 0, 0, 0);
      S[mt] = s;
    }
    #pragma unroll
    for (int mt = 0; mt < 4; mt++) {
      float e[4];
      #pragma unroll
      for (int r = 0; r < 4; r++) {
        int kg = kb + mt * 16 + g * 4 + r;
        e[r] = (kg <= q_glob) ? exp2f(S[mt][r]) : 0.f;
      }
      lsum += (e[0] + e[1]) + (e[2] + e[3]);
      ushort4 o; o.x = f2b(e[0]); o.y = f2b(e[1]); o.z = f2b(e[2]); o.w = f2b(e[3]);
      *(ushort4*)&Plds[wv][m][mt * 16 + g * 4] = o;
    }
    short8 pa0 = *(const short8*)&Plds[wv][m][g * 8];
    short8 pa1 = *(const short8*)&Plds[wv][m][32 + g * 8];
    #pragma unroll
    for (int nt = 0; nt < 4; nt++) {
      O[nt] = __builtin_amdgcn_mfma_f32_16x16x32_bf16(pa0, vf[2 * nt], O[nt], 0, 0, 0);
      O[nt] = __builtin_amdgcn_mfma_f32_16x16x32_bf16(pa1, vf[2 * nt + 1], O[nt], 0, 0, 0);
    }
  }

  // reduce l across the 4 g-lanes sharing q=m, then normalize + store
  lsum += __shfl_xor(lsum, 16, 64);
  lsum += __shfl_xor(lsum, 32, 64);
  float li[4];
  #pragma unroll
  for (int r = 0; r < 4; r++) li[r] = 1.0f / __shfl(lsum, g * 4 + r, 64);
  const int b = bh >> 4, h = bh & 15;
  #pragma unroll
  for (int nt = 0; nt < 4; nt++)
    #pragma unroll
    for (int r = 0; r < 4; r++) {
      int trow = qbase + g * 4 + r;
      int col = h * 64 + nt * 16 + m;
      Y[(size_t)(b * T_ + trow) * C_ + col] = f2b(O[nt][r] * li[r]);
    }
}

// ---------------- launch ----------------

extern "C" void kernel_launch(void* const* d_in, const int* in_sizes, int n_in,
                              void* d_out, int out_size, void* d_ws, size_t ws_size,
                              hipStream_t stream) {
  (void)in_sizes; (void)n_in; (void)out_size; (void)ws_size;
  const float* x      = (const float*)d_in[0];
  const float* cosp   = (const float*)d_in[1];
  const float* sinp   = (const float*)d_in[2];
  const float* w_qkv  = (const float*)d_in[3];
  const float* w_proj = (const float*)d_in[4];
  float* out = (float*)d_out;

  char* ws = (char*)d_ws;
  double* sums = (double*)ws;                       // 16 B
  float*  ams  = (float*)(ws + 16);                 // 8 B
  unsigned short* wqkv_b  = (unsigned short*)(ws + 256);            // 6 MB
  unsigned short* wproj_b = wqkv_b + (size_t)N3C * C_;              // 2 MB
  unsigned short* xb      = wproj_b + (size_t)C_ * C_;              // 8 MB
  unsigned short* qkv_b   = xb + (size_t)M_ * C_;                   // 24 MB
  unsigned short* Qb      = qkv_b + (size_t)M_ * N3C;               // 8 MB
  unsigned short* Kb      = Qb + (size_t)B_ * H_ * T_ * D_;         // 8 MB
  unsigned short* Vtb     = Kb + (size_t)B_ * H_ * T_ * D_;         // 8 MB
  unsigned short* yb      = Vtb + (size_t)B_ * H_ * T_ * D_;        // 8 MB

  zero_sums<<<1, 64, 0, stream>>>(sums);
  abs_sum_kernel<<<1024, 256, 0, stream>>>(w_qkv, (3 * C_ * C_) / 4, sums + 0);
  abs_sum_kernel<<<512, 256, 0, stream>>>(w_proj, (C_ * C_) / 4, sums + 1);
  ternarize_kernel<<<(3 * C_ * C_) / 256, 256, 0, stream>>>(w_qkv, wqkv_b, 3 * C_ * C_,
                                                            sums + 0, 1.0f / (3 * C_ * C_), ams + 0);
  ternarize_kernel<<<(C_ * C_) / 256, 256, 0, stream>>>(w_proj, wproj_b, C_ * C_,
                                                        sums + 1, 1.0f / (C_ * C_), ams + 1);
  cvt_f32_bf16<<<(M_ * C_ / 4 + 255) / 256, 256, 0, stream>>>(x, xb, M_ * C_ / 4);
  gemm128<1><<<dim3(N3C / 128, M_ / 128), 256, 0, stream>>>(xb, wqkv_b, ams + 0, qkv_b, N3C, C_);
  rope_pack<<<(M_ * 512) / 256, 256, 0, stream>>>(qkv_b, cosp, sinp, Qb, Kb);
  v_transpose<<<dim3(T_ / 64, B_ * H_), 256, 0, stream>>>(qkv_b, Vtb);
  flash_mfma<<<dim3(T_ / 64, B_ * H_), 256, 0, stream>>>(Qb, Kb, Vtb, yb);
  gemm128<0><<<dim3(C_ / 128, M_ / 128), 256, 0, stream>>>(yb, wproj_b, ams + 1, out, C_, C_);
}

// Round 5
// 292.418 us; speedup vs baseline: 10.2554x; 1.5982x over previous
//
#include <hip/hip_runtime.h>
#include <hip/hip_bf16.h>

// Problem constants: B=2, T=2048, C=1024, H=16, D=64
#define B_ 2
#define T_ 2048
#define C_ 1024
#define H_ 16
#define D_ 64
#define M_ 4096
#define N3C 3072

using short8  = __attribute__((ext_vector_type(8))) short;
using floatx4 = __attribute__((ext_vector_type(4))) float;
typedef unsigned int u32;

__device__ __forceinline__ unsigned short f2b(float f) {
  __hip_bfloat16 h = __float2bfloat16(f);
  return *reinterpret_cast<unsigned short*>(&h);
}
__device__ __forceinline__ float b2f(unsigned short u) {
  union { unsigned int i; float f; } x; x.i = ((unsigned int)u) << 16; return x.f;
}

// async global->LDS, 16B per lane; LDS dest = wave-uniform base + lane*16
__device__ __forceinline__ void gll16(const void* g, void* l) {
  __builtin_amdgcn_global_load_lds((const __attribute__((address_space(1))) u32*)g,
                                   (__attribute__((address_space(3))) u32*)l, 16, 0, 0);
}

// ---------------- ternarization ----------------

__global__ void zero_sums(double* sums) {
  if (threadIdx.x < 2) sums[threadIdx.x] = 0.0;
}

__global__ void abs_sum_kernel(const float* __restrict__ w, int n4, double* out) {
  int stride = gridDim.x * blockDim.x;
  double s = 0.0;
  for (int i = blockIdx.x * blockDim.x + threadIdx.x; i < n4; i += stride) {
    float4 v = ((const float4*)w)[i];
    s += (double)fabsf(v.x) + (double)fabsf(v.y) + (double)fabsf(v.z) + (double)fabsf(v.w);
  }
  #pragma unroll
  for (int off = 32; off > 0; off >>= 1)
    s += __shfl_down(s, off, 64);
  if ((threadIdx.x & 63) == 0) atomicAdd(out, s);
}

// exact {-1,0,+1} in bf16; abs_mean applied fp32 in GEMM epilogue
__global__ void ternarize_kernel(const float* __restrict__ w, unsigned short* __restrict__ out,
                                 int n, const double* sum, float inv_n, float* am_out) {
  float am = fmaxf((float)(*sum) * inv_n, 1e-5f);
  int i = blockIdx.x * blockDim.x + threadIdx.x;
  if (i == 0) *am_out = am;
  if (i < n) {
    float thr = 0.7f * am;
    float x = w[i];
    out[i] = (x > thr) ? 0x3F80u : ((x < -thr) ? 0xBF80u : 0u);
  }
}

__global__ void cvt_f32_bf16(const float* __restrict__ in, unsigned short* __restrict__ out, int n4) {
  int i = blockIdx.x * blockDim.x + threadIdx.x;
  if (i < n4) {
    float4 v = ((const float4*)in)[i];
    ushort4 o; o.x = f2b(v.x); o.y = f2b(v.y); o.z = f2b(v.z); o.w = f2b(v.w);
    ((ushort4*)out)[i] = o;
  }
}

// ---------------- m97-style MFMA GEMM: C[M,N] = (A[M,K] @ W[N,K]^T) * scale ----
// 128x128 tile, BK=32, 256 threads (2x2 waves of 64x64), global_load_lds staging.

template<int OUT_BF16>
__global__ __launch_bounds__(256) void gemm128(const unsigned short* __restrict__ A,
                                               const unsigned short* __restrict__ W,
                                               const float* __restrict__ scale_ptr,
                                               void* __restrict__ Cout,
                                               int N, int K) {
  __shared__ __attribute__((aligned(16))) unsigned short As[128 * 32];
  __shared__ __attribute__((aligned(16))) unsigned short Ws[128 * 32];
  const int tid = threadIdx.x, lane = tid & 63, wv = tid >> 6;
  const int m = lane & 15, g = lane >> 4;
  const int m0 = blockIdx.y * 128, n0 = blockIdx.x * 128;
  const int wm = (wv >> 1) * 64, wn = (wv & 1) * 64;

  const int srow = wv * 16 + (lane >> 2);
  const int skoff = (lane & 3) * 8;
  const unsigned short* ga0 = A + (size_t)(m0 + srow) * K + skoff;
  const unsigned short* ga1 = A + (size_t)(m0 + 64 + srow) * K + skoff;
  const unsigned short* gw0 = W + (size_t)(n0 + srow) * K + skoff;
  const unsigned short* gw1 = W + (size_t)(n0 + 64 + srow) * K + skoff;
  unsigned short* la0 = As + (wv * 16) * 32;
  unsigned short* la1 = As + (64 + wv * 16) * 32;
  unsigned short* lw0 = Ws + (wv * 16) * 32;
  unsigned short* lw1 = Ws + (64 + wv * 16) * 32;

  floatx4 acc[4][4] = {};
  for (int kc = 0; kc < K; kc += 32) {
    __syncthreads();
    gll16(ga0, la0); gll16(ga1, la1); gll16(gw0, lw0); gll16(gw1, lw1);
    ga0 += 32; ga1 += 32; gw0 += 32; gw1 += 32;
    __syncthreads();
    short8 af[4], wf[4];
    #pragma unroll
    for (int r = 0; r < 4; r++)
      af[r] = *(const short8*)&As[(wm + r * 16 + m) * 32 + g * 8];
    #pragma unroll
    for (int c = 0; c < 4; c++)
      wf[c] = *(const short8*)&Ws[(wn + c * 16 + m) * 32 + g * 8];
    #pragma unroll
    for (int r = 0; r < 4; r++)
      #pragma unroll
      for (int c = 0; c < 4; c++)
        acc[r][c] = __builtin_amdgcn_mfma_f32_16x16x32_bf16(af[r], wf[c], acc[r][c], 0, 0, 0);
  }

  const float scale = *scale_ptr;
  #pragma unroll
  for (int r = 0; r < 4; r++)
    #pragma unroll
    for (int c = 0; c < 4; c++)
      #pragma unroll
      for (int i = 0; i < 4; i++) {
        int row = m0 + wm + r * 16 + g * 4 + i;
        int col = n0 + wn + c * 16 + m;
        float val = acc[r][c][i] * scale;
        if (OUT_BF16) ((unsigned short*)Cout)[(size_t)row * N + col] = f2b(val);
        else          ((float*)Cout)[(size_t)row * N + col] = val;
      }
}

// ---------------- RoPE + pack Q,K -> [bh][t][d] bf16 (Q pre-scaled by log2e/8) ----

__global__ void rope_pack(const unsigned short* __restrict__ qkv,  // bf16 [4096][3072]
                          const float* __restrict__ cosp, const float* __restrict__ sinp,
                          unsigned short* __restrict__ Qb, unsigned short* __restrict__ Kb) {
  const float QSC = 0.125f * 1.44269504088896340736f;   // (1/sqrt(D)) * log2(e)
  int i = blockIdx.x * blockDim.x + threadIdx.x;  // 0 .. M_*512-1
  int row = i >> 9;                               // b*T+t
  int cp = i & 511;
  int h = cp >> 5, p = cp & 31;
  int t = row & (T_ - 1);
  int b = row >> 11;
  int bh = b * H_ + h;
  size_t qb = (size_t)row * N3C + h * 64;
  float q1 = b2f(qkv[qb + p]),      q2 = b2f(qkv[qb + p + 32]);
  float k1 = b2f(qkv[qb + C_ + p]), k2 = b2f(qkv[qb + C_ + p + 32]);
  float c1 = cosp[t * 64 + p], c2 = cosp[t * 64 + p + 32];
  float s1 = sinp[t * 64 + p], s2 = sinp[t * 64 + p + 32];
  size_t ob = (size_t)bh * T_ * 64 + (size_t)t * 64;
  Qb[ob + p]      = f2b((q1 * c1 - q2 * s1) * QSC);
  Qb[ob + p + 32] = f2b((q2 * c2 + q1 * s2) * QSC);
  Kb[ob + p]      = f2b(k1 * c1 - k2 * s1);
  Kb[ob + p + 32] = f2b(k2 * c2 + k1 * s2);
}

// ---------------- V transpose -> Vtb[bh][d][t] bf16 ----------------

__global__ __launch_bounds__(256) void v_transpose(const unsigned short* __restrict__ qkv,
                                                   unsigned short* __restrict__ Vtb) {
  __shared__ unsigned short L[64][65];
  int bh = blockIdx.y;
  int t0 = blockIdx.x * 64;
  int b = bh >> 4, h = bh & 15;
  #pragma unroll
  for (int it = 0; it < 16; it++) {
    int idx = it * 256 + threadIdx.x;
    int tl = idx >> 6, d = idx & 63;
    L[tl][d] = qkv[(size_t)(b * T_ + t0 + tl) * N3C + 2 * C_ + h * 64 + d];
  }
  __syncthreads();
  #pragma unroll
  for (int it = 0; it < 16; it++) {
    int idx = it * 256 + threadIdx.x;
    int dr = idx >> 6, tl = idx & 63;
    Vtb[(size_t)bh * 64 * T_ + (size_t)dr * T_ + t0 + tl] = L[tl][dr];
  }
}

// ---------------- MFMA flash attention, m=0 softmax, LDS-staged K/V ----------
// Block = 4 waves, one 64-q strip pair {s, 31-s} (uniform 33 tiles/block).
// K/V tiles double-buffered in LDS via global_load_lds, XOR-swizzled 16B chunks.
// Wave wv owns q rows [s*64+wv*16, +16). S^T = K*Q^T; P via LDS; O += P*V.

__global__ __launch_bounds__(256) void flash_mfma(const unsigned short* __restrict__ Qb,
                                                  const unsigned short* __restrict__ Kb,
                                                  const unsigned short* __restrict__ Vtb,
                                                  unsigned short* __restrict__ Y) {
  __shared__ __align__(16) unsigned short Ktile[2][64][64];   // [buf][t][d]
  __shared__ __align__(16) unsigned short Vtile[2][64][64];   // [buf][d][t]
  __shared__ __align__(16) unsigned short Plds[4][16][72];
  const int lane = threadIdx.x & 63;
  const int wv = threadIdx.x >> 6;
  const int m = lane & 15, g = lane >> 4;
  const int bh = blockIdx.y;
  const int b = bh >> 4, h = bh & 15;
  const size_t hb = (size_t)bh * T_ * 64;
  const unsigned short* Kbh = Kb + hb;
  const unsigned short* Vbh = Vtb + hb;     // [64][T_] for this bh
  const int r8 = lane >> 3, cc8 = lane & 7;
  const int gcol = ((cc8 ^ r8) << 3);       // swizzled global chunk

  #pragma unroll
  for (int sp = 0; sp < 2; sp++) {
    const int s = sp ? (31 - blockIdx.x) : blockIdx.x;
    const int qbase = s * 64 + wv * 16;
    const int q_glob = qbase + m;
    const int ntiles = s + 1;

    const unsigned short* qp = Qb + hb + (size_t)(qbase + m) * 64 + g * 8;
    short8 qf0 = *(const short8*)qp;
    short8 qf1 = *(const short8*)(qp + 32);

    floatx4 O[4] = {};
    float lsum = 0.f;

    if (sp) __syncthreads();   // previous strip's readers done before restage
    // stage tile 0 -> buf 0 (wave wv stages its 16-row slice of K and V)
    #pragma unroll
    for (int cc = 0; cc < 2; cc++) {
      int row = wv * 16 + cc * 8;
      gll16(Kbh + (size_t)(row + r8) * 64 + gcol, &Ktile[0][row][0]);
      gll16(Vbh + (size_t)(row + r8) * T_ + gcol, &Vtile[0][row][0]);
    }

    for (int kt = 0; kt < ntiles; kt++) {
      const int buf = kt & 1;
      const int kb = kt * 64;
      __syncthreads();                       // stage(kt) visible (vmcnt drained)
      if (kt + 1 < ntiles) {                 // stream next tile into other buffer
        const int kb2 = kb + 64;
        #pragma unroll
        for (int cc = 0; cc < 2; cc++) {
          int row = wv * 16 + cc * 8;
          gll16(Kbh + (size_t)(kb2 + row + r8) * 64 + gcol, &Ktile[1 - buf][row][0]);
          gll16(Vbh + (size_t)(row + r8) * T_ + kb2 + gcol, &Vtile[1 - buf][row][0]);
        }
      }
      // S^T = K * Q^T  (swizzled reads: G[r][c] = LDS[r][c ^ (r&7)])
      floatx4 S[4];
      #pragma unroll
      for (int mt = 0; mt < 4; mt++) {
        int row = mt * 16 + m;
        short8 kf0 = *(const short8*)&Ktile[buf][row][(g ^ (m & 7)) << 3];
        short8 kf1 = *(const short8*)&Ktile[buf][row][((g + 4) ^ (m & 7)) << 3];
        floatx4 sv = {};
        sv = __builtin_amdgcn_mfma_f32_16x16x32_bf16(kf0, qf0, sv, 0, 0, 0);
        sv = __builtin_amdgcn_mfma_f32_16x16x32_bf16(kf1, qf1, sv, 0, 0, 0);
        S[mt] = sv;
      }
      if (kt + 1 < ntiles) {                 // full (unmasked) tile
        #pragma unroll
        for (int mt = 0; mt < 4; mt++) {
          float e0 = exp2f(S[mt][0]), e1 = exp2f(S[mt][1]);
          float e2 = exp2f(S[mt][2]), e3 = exp2f(S[mt][3]);
          lsum += (e0 + e1) + (e2 + e3);
          ushort4 o; o.x = f2b(e0); o.y = f2b(e1); o.z = f2b(e2); o.w = f2b(e3);
          *(ushort4*)&Plds[wv][m][mt * 16 + g * 4] = o;
        }
      } else {                               // diagonal tile: causal mask
        #pragma unroll
        for (int mt = 0; mt < 4; mt++) {
          float e[4];
          #pragma unroll
          for (int r = 0; r < 4; r++) {
            int kg = kb + mt * 16 + g * 4 + r;
            e[r] = (kg <= q_glob) ? exp2f(S[mt][r]) : 0.f;
          }
          lsum += (e[0] + e[1]) + (e[2] + e[3]);
          ushort4 o; o.x = f2b(e[0]); o.y = f2b(e[1]); o.z = f2b(e[2]); o.w = f2b(e[3]);
          *(ushort4*)&Plds[wv][m][mt * 16 + g * 4] = o;
        }
      }
      short8 pa0 = *(const short8*)&Plds[wv][m][g * 8];
      short8 pa1 = *(const short8*)&Plds[wv][m][32 + g * 8];
      #pragma unroll
      for (int nt = 0; nt < 4; nt++) {
        int row = nt * 16 + m;
        short8 v0 = *(const short8*)&Vtile[buf][row][(g ^ (m & 7)) << 3];
        short8 v1 = *(const short8*)&Vtile[buf][row][((g + 4) ^ (m & 7)) << 3];
        O[nt] = __builtin_amdgcn_mfma_f32_16x16x32_bf16(pa0, v0, O[nt], 0, 0, 0);
        O[nt] = __builtin_amdgcn_mfma_f32_16x16x32_bf16(pa1, v1, O[nt], 0, 0, 0);
      }
    }

    // reduce l across g-lanes sharing q=m, normalize, store
    lsum += __shfl_xor(lsum, 16, 64);
    lsum += __shfl_xor(lsum, 32, 64);
    float li[4];
    #pragma unroll
    for (int r = 0; r < 4; r++) li[r] = 1.0f / __shfl(lsum, g * 4 + r, 64);
    #pragma unroll
    for (int nt = 0; nt < 4; nt++)
      #pragma unroll
      for (int r = 0; r < 4; r++) {
        int trow = qbase + g * 4 + r;
        int col = h * 64 + nt * 16 + m;
        Y[(size_t)(b * T_ + trow) * C_ + col] = f2b(O[nt][r] * li[r]);
      }
  }
}

// ---------------- launch ----------------

extern "C" void kernel_launch(void* const* d_in, const int* in_sizes, int n_in,
                              void* d_out, int out_size, void* d_ws, size_t ws_size,
                              hipStream_t stream) {
  (void)in_sizes; (void)n_in; (void)out_size; (void)ws_size;
  const float* x      = (const float*)d_in[0];
  const float* cosp   = (const float*)d_in[1];
  const float* sinp   = (const float*)d_in[2];
  const float* w_qkv  = (const float*)d_in[3];
  const float* w_proj = (const float*)d_in[4];
  float* out = (float*)d_out;

  char* ws = (char*)d_ws;
  double* sums = (double*)ws;                       // 16 B
  float*  ams  = (float*)(ws + 16);                 // 8 B
  unsigned short* wqkv_b  = (unsigned short*)(ws + 256);            // 6 MB
  unsigned short* wproj_b = wqkv_b + (size_t)N3C * C_;              // 2 MB
  unsigned short* xb      = wproj_b + (size_t)C_ * C_;              // 8 MB
  unsigned short* qkv_b   = xb + (size_t)M_ * C_;                   // 24 MB
  unsigned short* Qb      = qkv_b + (size_t)M_ * N3C;               // 8 MB
  unsigned short* Kb      = Qb + (size_t)B_ * H_ * T_ * D_;         // 8 MB
  unsigned short* Vtb     = Kb + (size_t)B_ * H_ * T_ * D_;         // 8 MB
  unsigned short* yb      = Vtb + (size_t)B_ * H_ * T_ * D_;        // 8 MB

  zero_sums<<<1, 64, 0, stream>>>(sums);
  abs_sum_kernel<<<1024, 256, 0, stream>>>(w_qkv, (3 * C_ * C_) / 4, sums + 0);
  abs_sum_kernel<<<512, 256, 0, stream>>>(w_proj, (C_ * C_) / 4, sums + 1);
  ternarize_kernel<<<(3 * C_ * C_) / 256, 256, 0, stream>>>(w_qkv, wqkv_b, 3 * C_ * C_,
                                                            sums + 0, 1.0f / (3 * C_ * C_), ams + 0);
  ternarize_kernel<<<(C_ * C_) / 256, 256, 0, stream>>>(w_proj, wproj_b, C_ * C_,
                                                        sums + 1, 1.0f / (C_ * C_), ams + 1);
  cvt_f32_bf16<<<(M_ * C_ / 4 + 255) / 256, 256, 0, stream>>>(x, xb, M_ * C_ / 4);
  gemm128<1><<<dim3(N3C / 128, M_ / 128), 256, 0, stream>>>(xb, wqkv_b, ams + 0, qkv_b, N3C, C_);
  rope_pack<<<(M_ * 512) / 256, 256, 0, stream>>>(qkv_b, cosp, sinp, Qb, Kb);
  v_transpose<<<dim3(T_ / 64, B_ * H_), 256, 0, stream>>>(qkv_b, Vtb);
  flash_mfma<<<dim3(16, B_ * H_), 256, 0, stream>>>(Qb, Kb, Vtb, yb);
  gemm128<0><<<dim3(C_ / 128, M_ / 128), 256, 0, stream>>>(yb, wproj_b, ams + 1, out, C_, C_);
}

// Round 6
// 224.308 us; speedup vs baseline: 13.3694x; 1.3036x over previous
//
#include <hip/hip_runtime.h>
#include <hip/hip_bf16.h>

// Problem constants: B=2, T=2048, C=1024, H=16, D=64
#define B_ 2
#define T_ 2048
#define C_ 1024
#define H_ 16
#define D_ 64
#define M_ 4096
#define N3C 3072

using short8  = __attribute__((ext_vector_type(8))) short;
using floatx4 = __attribute__((ext_vector_type(4))) float;
typedef unsigned int u32;

__device__ __forceinline__ unsigned short f2b(float f) {
  __hip_bfloat16 h = __float2bfloat16(f);
  return *reinterpret_cast<unsigned short*>(&h);
}
__device__ __forceinline__ float b2f(unsigned short u) {
  union { unsigned int i; float f; } x; x.i = ((unsigned int)u) << 16; return x.f;
}

// async global->LDS, 16B per lane; LDS dest = wave-uniform base + lane*16
__device__ __forceinline__ void gll16(const void* g, void* l) {
  __builtin_amdgcn_global_load_lds((const __attribute__((address_space(1))) u32*)g,
                                   (__attribute__((address_space(3))) u32*)l, 16, 0, 0);
}

// ---------------- ternarization ----------------

__global__ void zero_sums(double* sums) {
  if (threadIdx.x < 2) sums[threadIdx.x] = 0.0;
}

// per-block LDS reduction -> ONE atomic per block (contended-atomic fix)
__global__ void abs_sum_kernel(const float* __restrict__ w, int n4, double* out) {
  __shared__ double red[4];
  int stride = gridDim.x * blockDim.x;
  double s = 0.0;
  for (int i = blockIdx.x * blockDim.x + threadIdx.x; i < n4; i += stride) {
    float4 v = ((const float4*)w)[i];
    s += (double)fabsf(v.x) + (double)fabsf(v.y) + (double)fabsf(v.z) + (double)fabsf(v.w);
  }
  #pragma unroll
  for (int off = 32; off > 0; off >>= 1)
    s += __shfl_down(s, off, 64);
  if ((threadIdx.x & 63) == 0) red[threadIdx.x >> 6] = s;
  __syncthreads();
  if (threadIdx.x == 0) atomicAdd(out, (red[0] + red[1]) + (red[2] + red[3]));
}

// both weight tensors in one launch; exact {-1,0,+1} bf16
__global__ void ternarize_all(const float* __restrict__ wq, const float* __restrict__ wp,
                              unsigned short* __restrict__ oq, unsigned short* __restrict__ op,
                              const double* __restrict__ sums, float* __restrict__ ams) {
  const int NQ = 3 * C_ * C_;
  const int NP = C_ * C_;
  int i = blockIdx.x * blockDim.x + threadIdx.x;
  float am0 = fmaxf((float)(sums[0] * (1.0 / NQ)), 1e-5f);
  float am1 = fmaxf((float)(sums[1] * (1.0 / NP)), 1e-5f);
  if (i == 0) { ams[0] = am0; ams[1] = am1; }
  if (i < NQ) {
    float thr = 0.7f * am0, x = wq[i];
    oq[i] = (x > thr) ? 0x3F80u : ((x < -thr) ? 0xBF80u : 0u);
  } else if (i < NQ + NP) {
    int j = i - NQ;
    float thr = 0.7f * am1, x = wp[j];
    op[j] = (x > thr) ? 0x3F80u : ((x < -thr) ? 0xBF80u : 0u);
  }
}

__global__ void cvt_f32_bf16(const float* __restrict__ in, unsigned short* __restrict__ out, int n4) {
  int i = blockIdx.x * blockDim.x + threadIdx.x;
  if (i < n4) {
    float4 v = ((const float4*)in)[i];
    ushort4 o; o.x = f2b(v.x); o.y = f2b(v.y); o.z = f2b(v.z); o.w = f2b(v.w);
    ((ushort4*)out)[i] = o;
  }
}

// ---------------- m97-style MFMA GEMM: C[M,N] = (A[M,K] @ W[N,K]^T) * scale ----
// 128x128 tile, BK=32, 256 threads (2x2 waves of 64x64), global_load_lds staging.

template<int OUT_BF16>
__global__ __launch_bounds__(256) void gemm128(const unsigned short* __restrict__ A,
                                               const unsigned short* __restrict__ W,
                                               const float* __restrict__ scale_ptr,
                                               void* __restrict__ Cout,
                                               int N, int K) {
  __shared__ __attribute__((aligned(16))) unsigned short As[128 * 32];
  __shared__ __attribute__((aligned(16))) unsigned short Ws[128 * 32];
  const int tid = threadIdx.x, lane = tid & 63, wv = tid >> 6;
  const int m = lane & 15, g = lane >> 4;
  const int m0 = blockIdx.y * 128, n0 = blockIdx.x * 128;
  const int wm = (wv >> 1) * 64, wn = (wv & 1) * 64;

  const int srow = wv * 16 + (lane >> 2);
  const int skoff = (lane & 3) * 8;
  const unsigned short* ga0 = A + (size_t)(m0 + srow) * K + skoff;
  const unsigned short* ga1 = A + (size_t)(m0 + 64 + srow) * K + skoff;
  const unsigned short* gw0 = W + (size_t)(n0 + srow) * K + skoff;
  const unsigned short* gw1 = W + (size_t)(n0 + 64 + srow) * K + skoff;
  unsigned short* la0 = As + (wv * 16) * 32;
  unsigned short* la1 = As + (64 + wv * 16) * 32;
  unsigned short* lw0 = Ws + (wv * 16) * 32;
  unsigned short* lw1 = Ws + (64 + wv * 16) * 32;

  floatx4 acc[4][4] = {};
  for (int kc = 0; kc < K; kc += 32) {
    __syncthreads();
    gll16(ga0, la0); gll16(ga1, la1); gll16(gw0, lw0); gll16(gw1, lw1);
    ga0 += 32; ga1 += 32; gw0 += 32; gw1 += 32;
    __syncthreads();
    short8 af[4], wf[4];
    #pragma unroll
    for (int r = 0; r < 4; r++)
      af[r] = *(const short8*)&As[(wm + r * 16 + m) * 32 + g * 8];
    #pragma unroll
    for (int c = 0; c < 4; c++)
      wf[c] = *(const short8*)&Ws[(wn + c * 16 + m) * 32 + g * 8];
    #pragma unroll
    for (int r = 0; r < 4; r++)
      #pragma unroll
      for (int c = 0; c < 4; c++)
        acc[r][c] = __builtin_amdgcn_mfma_f32_16x16x32_bf16(af[r], wf[c], acc[r][c], 0, 0, 0);
  }

  const float scale = *scale_ptr;
  #pragma unroll
  for (int r = 0; r < 4; r++)
    #pragma unroll
    for (int c = 0; c < 4; c++)
      #pragma unroll
      for (int i = 0; i < 4; i++) {
        int row = m0 + wm + r * 16 + g * 4 + i;
        int col = n0 + wn + c * 16 + m;
        float val = acc[r][c][i] * scale;
        if (OUT_BF16) ((unsigned short*)Cout)[(size_t)row * N + col] = f2b(val);
        else          ((float*)Cout)[(size_t)row * N + col] = val;
      }
}

// ---------------- fused RoPE-pack + V-transpose ----------------
// block = (t-tile of 64, bh). RoPE q,k -> Qb,Kb [bh][t][d] (Q pre-scaled
// log2e/8); V -> Vtb [bh][d][t] via LDS transpose.

__global__ __launch_bounds__(256) void rope_vtrans(const unsigned short* __restrict__ qkv,
                                                   const float* __restrict__ cosp,
                                                   const float* __restrict__ sinp,
                                                   unsigned short* __restrict__ Qb,
                                                   unsigned short* __restrict__ Kb,
                                                   unsigned short* __restrict__ Vtb) {
  __shared__ unsigned short L[64][65];
  const float QSC = 0.125f * 1.44269504088896340736f;   // (1/sqrt(D)) * log2(e)
  const int bh = blockIdx.y, t0 = blockIdx.x * 64;
  const int b = bh >> 4, h = bh & 15;
  const size_t hb = (size_t)bh * T_ * 64;
  // RoPE: 64 t x 32 p pairs
  #pragma unroll
  for (int it = 0; it < 8; it++) {
    int idx = it * 256 + threadIdx.x;
    int tl = idx >> 5, p = idx & 31, t = t0 + tl;
    size_t rb = (size_t)(b * T_ + t) * N3C + h * 64;
    float q1 = b2f(qkv[rb + p]),      q2 = b2f(qkv[rb + p + 32]);
    float k1 = b2f(qkv[rb + C_ + p]), k2 = b2f(qkv[rb + C_ + p + 32]);
    float c1 = cosp[t * 64 + p], c2 = cosp[t * 64 + p + 32];
    float s1 = sinp[t * 64 + p], s2 = sinp[t * 64 + p + 32];
    size_t ob = hb + (size_t)t * 64;
    Qb[ob + p]      = f2b((q1 * c1 - q2 * s1) * QSC);
    Qb[ob + p + 32] = f2b((q2 * c2 + q1 * s2) * QSC);
    Kb[ob + p]      = f2b(k1 * c1 - k2 * s1);
    Kb[ob + p + 32] = f2b(k2 * c2 + k1 * s2);
  }
  // V transpose
  #pragma unroll
  for (int it = 0; it < 16; it++) {
    int idx = it * 256 + threadIdx.x;
    int tl = idx >> 6, d = idx & 63;
    L[tl][d] = qkv[(size_t)(b * T_ + t0 + tl) * N3C + 2 * C_ + h * 64 + d];
  }
  __syncthreads();
  #pragma unroll
  for (int it = 0; it < 16; it++) {
    int idx = it * 256 + threadIdx.x;
    int dr = idx >> 6, tl = idx & 63;
    Vtb[hb + (size_t)dr * T_ + t0 + tl] = L[tl][dr];
  }
}

// ---------------- MFMA flash attention, m=0 softmax, LDS-staged K/V ----------
// 256 blocks; gid -> (bh, pair) with XCD locality: all 8 pair-blocks of a bh
// share gid%8 (same XCD heuristic) so K/V re-reads hit one XCD's L2.
// Block = 4 waves, strip pair {s, 15-s} of 128 q-rows (34 tiles, uniform).
// Wave owns 32 q (2 accumulator sets). K/V double-buffered via global_load_lds,
// XOR-swizzled 16B chunks. S^T = K*Q^T; P via per-wave LDS; O += P*V.

__global__ __launch_bounds__(256) void flash_mfma(const unsigned short* __restrict__ Qb,
                                                  const unsigned short* __restrict__ Kb,
                                                  const unsigned short* __restrict__ Vtb,
                                                  unsigned short* __restrict__ Y) {
  __shared__ __align__(16) unsigned short Ktile[2][64][64];   // [buf][t][d]
  __shared__ __align__(16) unsigned short Vtile[2][64][64];   // [buf][d][t]
  __shared__ __align__(16) unsigned short Plds[4][16][72];
  const int lane = threadIdx.x & 63;
  const int wv = threadIdx.x >> 6;
  const int m = lane & 15, g = lane >> 4;
  const int gid = blockIdx.x;
  const int xcd = gid & 7, idx = gid >> 3;
  const int bh = xcd * 4 + (idx >> 3);
  const int pr = idx & 7;
  const int b = bh >> 4, h = bh & 15;
  const size_t hb = (size_t)bh * T_ * 64;
  const unsigned short* Kbh = Kb + hb;
  const unsigned short* Vbh = Vtb + hb;     // [64][T_]
  const int r8 = lane >> 3, cc8 = lane & 7;
  const int gcol = ((cc8 ^ r8) << 3);       // swizzled global chunk

  #pragma unroll
  for (int sp = 0; sp < 2; sp++) {
    const int s = sp ? (15 - pr) : pr;
    const int ntiles = 2 * s + 2;
    const int qb0 = s * 128 + wv * 32;      // qset0 base (16 rows)
    const int qb1 = qb0 + 16;               // qset1 base

    const unsigned short* qp0 = Qb + hb + (size_t)(qb0 + m) * 64 + g * 8;
    short8 qf00 = *(const short8*)qp0;
    short8 qf01 = *(const short8*)(qp0 + 32);
    const unsigned short* qp1 = qp0 + 16 * 64;
    short8 qf10 = *(const short8*)qp1;
    short8 qf11 = *(const short8*)(qp1 + 32);

    floatx4 O0[4] = {}, O1[4] = {};
    float ls0 = 0.f, ls1 = 0.f;

    if (sp) __syncthreads();   // previous strip's readers done before restage
    #pragma unroll
    for (int cc = 0; cc < 2; cc++) {        // stage tile 0 -> buf 0
      int row = wv * 16 + cc * 8;
      gll16(Kbh + (size_t)(row + r8) * 64 + gcol, &Ktile[0][row][0]);
      gll16(Vbh + (size_t)(row + r8) * T_ + gcol, &Vtile[0][row][0]);
    }

    for (int kt = 0; kt < ntiles; kt++) {
      const int buf = kt & 1;
      const int kb = kt * 64;
      __syncthreads();                       // stage(kt) visible
      if (kt + 1 < ntiles) {                 // stream next tile
        const int kb2 = kb + 64;
        #pragma unroll
        for (int cc = 0; cc < 2; cc++) {
          int row = wv * 16 + cc * 8;
          gll16(Kbh + (size_t)(kb2 + row + r8) * 64 + gcol, &Ktile[1 - buf][row][0]);
          gll16(Vbh + (size_t)(row + r8) * T_ + kb2 + gcol, &Vtile[1 - buf][row][0]);
        }
      }
      if (kb > qb0 + 31) continue;           // whole wave past causal frontier

      auto do_qset = [&](short8 qa, short8 qb_, int qbase, float& lsum, floatx4* O) {
        floatx4 S[4];
        #pragma unroll
        for (int mt = 0; mt < 4; mt++) {
          int row = mt * 16 + m;
          short8 kf0 = *(const short8*)&Ktile[buf][row][(g ^ (m & 7)) << 3];
          short8 kf1 = *(const short8*)&Ktile[buf][row][((g + 4) ^ (m & 7)) << 3];
          floatx4 sv = {};
          sv = __builtin_amdgcn_mfma_f32_16x16x32_bf16(kf0, qa, sv, 0, 0, 0);
          sv = __builtin_amdgcn_mfma_f32_16x16x32_bf16(kf1, qb_, sv, 0, 0, 0);
          S[mt] = sv;
        }
        if (kb + 64 <= qbase) {              // fully unmasked tile
          #pragma unroll
          for (int mt = 0; mt < 4; mt++) {
            float e0 = exp2f(S[mt][0]), e1 = exp2f(S[mt][1]);
            float e2 = exp2f(S[mt][2]), e3 = exp2f(S[mt][3]);
            lsum += (e0 + e1) + (e2 + e3);
            ushort4 o; o.x = f2b(e0); o.y = f2b(e1); o.z = f2b(e2); o.w = f2b(e3);
            *(ushort4*)&Plds[wv][m][mt * 16 + g * 4] = o;
          }
        } else {                             // diagonal zone: causal mask
          const int q_glob = qbase + m;
          #pragma unroll
          for (int mt = 0; mt < 4; mt++) {
            float e[4];
            #pragma unroll
            for (int r = 0; r < 4; r++) {
              int kg = kb + mt * 16 + g * 4 + r;
              e[r] = (kg <= q_glob) ? exp2f(S[mt][r]) : 0.f;
            }
            lsum += (e[0] + e[1]) + (e[2] + e[3]);
            ushort4 o; o.x = f2b(e[0]); o.y = f2b(e[1]); o.z = f2b(e[2]); o.w = f2b(e[3]);
            *(ushort4*)&Plds[wv][m][mt * 16 + g * 4] = o;
          }
        }
        short8 pa0 = *(const short8*)&Plds[wv][m][g * 8];
        short8 pa1 = *(const short8*)&Plds[wv][m][32 + g * 8];
        #pragma unroll
        for (int nt = 0; nt < 4; nt++) {
          int row = nt * 16 + m;
          short8 v0 = *(const short8*)&Vtile[buf][row][(g ^ (m & 7)) << 3];
          short8 v1 = *(const short8*)&Vtile[buf][row][((g + 4) ^ (m & 7)) << 3];
          O[nt] = __builtin_amdgcn_mfma_f32_16x16x32_bf16(pa0, v0, O[nt], 0, 0, 0);
          O[nt] = __builtin_amdgcn_mfma_f32_16x16x32_bf16(pa1, v1, O[nt], 0, 0, 0);
        }
      };

      do_qset(qf00, qf01, qb0, ls0, O0);                       // qset0
      if (kb <= qb1 + 15) do_qset(qf10, qf11, qb1, ls1, O1);   // qset1
    }

    // per-qset: reduce l across g-lanes sharing q=m, normalize, store
    #pragma unroll
    for (int j = 0; j < 2; j++) {
      float lsum = j ? ls1 : ls0;
      floatx4* O = j ? O1 : O0;
      const int qbase = j ? qb1 : qb0;
      lsum += __shfl_xor(lsum, 16, 64);
      lsum += __shfl_xor(lsum, 32, 64);
      float li[4];
      #pragma unroll
      for (int r = 0; r < 4; r++) li[r] = 1.0f / __shfl(lsum, g * 4 + r, 64);
      #pragma unroll
      for (int nt = 0; nt < 4; nt++)
        #pragma unroll
        for (int r = 0; r < 4; r++) {
          int trow = qbase + g * 4 + r;
          int col = h * 64 + nt * 16 + m;
          Y[(size_t)(b * T_ + trow) * C_ + col] = f2b(O[nt][r] * li[r]);
        }
    }
  }
}

// ---------------- launch ----------------

extern "C" void kernel_launch(void* const* d_in, const int* in_sizes, int n_in,
                              void* d_out, int out_size, void* d_ws, size_t ws_size,
                              hipStream_t stream) {
  (void)in_sizes; (void)n_in; (void)out_size; (void)ws_size;
  const float* x      = (const float*)d_in[0];
  const float* cosp   = (const float*)d_in[1];
  const float* sinp   = (const float*)d_in[2];
  const float* w_qkv  = (const float*)d_in[3];
  const float* w_proj = (const float*)d_in[4];
  float* out = (float*)d_out;

  char* ws = (char*)d_ws;
  double* sums = (double*)ws;                       // 16 B
  float*  ams  = (float*)(ws + 16);                 // 8 B
  unsigned short* wqkv_b  = (unsigned short*)(ws + 256);            // 6 MB
  unsigned short* wproj_b = wqkv_b + (size_t)N3C * C_;              // 2 MB
  unsigned short* xb      = wproj_b + (size_t)C_ * C_;              // 8 MB
  unsigned short* qkv_b   = xb + (size_t)M_ * C_;                   // 24 MB
  unsigned short* Qb      = qkv_b + (size_t)M_ * N3C;               // 8 MB
  unsigned short* Kb      = Qb + (size_t)B_ * H_ * T_ * D_;         // 8 MB
  unsigned short* Vtb     = Kb + (size_t)B_ * H_ * T_ * D_;         // 8 MB
  unsigned short* yb      = Vtb + (size_t)B_ * H_ * T_ * D_;        // 8 MB

  zero_sums<<<1, 64, 0, stream>>>(sums);
  abs_sum_kernel<<<256, 256, 0, stream>>>(w_qkv, (3 * C_ * C_) / 4, sums + 0);
  abs_sum_kernel<<<128, 256, 0, stream>>>(w_proj, (C_ * C_) / 4, sums + 1);
  ternarize_all<<<(4 * C_ * C_) / 256, 256, 0, stream>>>(w_qkv, w_proj, wqkv_b, wproj_b,
                                                         sums, ams);
  cvt_f32_bf16<<<(M_ * C_ / 4 + 255) / 256, 256, 0, stream>>>(x, xb, M_ * C_ / 4);
  gemm128<1><<<dim3(N3C / 128, M_ / 128), 256, 0, stream>>>(xb, wqkv_b, ams + 0, qkv_b, N3C, C_);
  rope_vtrans<<<dim3(T_ / 64, B_ * H_), 256, 0, stream>>>(qkv_b, cosp, sinp, Qb, Kb, Vtb);
  flash_mfma<<<256, 256, 0, stream>>>(Qb, Kb, Vtb, yb);
  gemm128<0><<<dim3(C_ / 128, M_ / 128), 256, 0, stream>>>(yb, wproj_b, ams + 1, out, C_, C_);
}